// Round 1
// baseline (419.316 us; speedup 1.0000x reference)
//
#include <hip/hip_runtime.h>
#include <cstdint>

// ---------------------------------------------------------------------------
// Attention (Luong general): out = softmax(dec @ (enc@W)^T) @ enc
// B=8, S_enc=S_dec=2048, H=512, fp32 in/out.
//
// Strategy: bf16 MFMA with split-precision (hi+lo bf16, 3-term) for the two
// matmuls that feed the softmax (logit gaps matter: logit std ~512, top-2 gap
// ~131, plain bf16 error std ~1.5 would flip argmaxes). PV matmul is plain
// bf16 (P near-one-hot, error ~0.02 << 0.108 threshold).
// ws usage ~253 MB: splits + enc_proj(hi/lo) + enc^T(bf16) + logits fp32
// (P bf16 overwrites logits rows in place after softmax).
// ---------------------------------------------------------------------------

#define DEVINL __device__ __forceinline__

typedef __attribute__((ext_vector_type(8))) short short8;
typedef __attribute__((ext_vector_type(4))) float f32x4;

DEVINL short f2bf(float x) {
    union { float f; uint32_t u; } v; v.f = x;
    uint32_t r = v.u + 0x7FFFu + ((v.u >> 16) & 1u);   // RNE
    return (short)(r >> 16);
}
DEVINL float bf2f(short h) {
    union { uint32_t u; float f; } v; v.u = ((uint32_t)(uint16_t)h) << 16;
    return v.f;
}

DEVINL void gload_lds16(const void* g, void* l) {
    __builtin_amdgcn_global_load_lds(
        (const __attribute__((address_space(1))) char*)g,
        (__attribute__((address_space(3))) char*)l, 16, 0, 0);
}

// ---------------------------------------------------------------------------
// split fp32 -> (hi, lo) bf16 arrays.  8 elems/thread, exact-cover grids.
// ---------------------------------------------------------------------------
__global__ __launch_bounds__(256)
void split_kernel(const float* __restrict__ x, short* __restrict__ hi,
                  short* __restrict__ lo)
{
    long i = ((long)blockIdx.x * 256 + threadIdx.x) * 8;
    f32x4 a = *(const f32x4*)(x + i);
    f32x4 b = *(const f32x4*)(x + i + 4);
    short8 h, l;
#pragma unroll
    for (int j = 0; j < 4; j++) {
        short ha = f2bf(a[j]); h[j] = ha;     l[j] = f2bf(a[j] - bf2f(ha));
        short hb = f2bf(b[j]); h[4 + j] = hb; l[4 + j] = f2bf(b[j] - bf2f(hb));
    }
    *(short8*)(hi + i) = h;
    *(short8*)(lo + i) = l;
}

// W[512k][512n] -> Wt_hi/lo[n][k]  (coalesced reads, tiny so strided writes ok)
__global__ __launch_bounds__(256)
void split_w_kernel(const float* __restrict__ w, short* __restrict__ wth,
                    short* __restrict__ wtl)
{
    int idx = blockIdx.x * 256 + threadIdx.x;   // k*512 + n
    int k = idx >> 9, n = idx & 511;
    float v = w[idx];
    short h = f2bf(v);
    wth[(long)n * 512 + k] = h;
    wtl[(long)n * 512 + k] = f2bf(v - bf2f(h));
}

// enc[b][s][e] fp32 -> enc_t[b][e][s] bf16 (hi only; PV B-operand)
__global__ __launch_bounds__(256)
void transpose_bf16_kernel(const float* __restrict__ x, short* __restrict__ xt)
{
    __shared__ short tile[32][33];
    const int b  = blockIdx.z;
    const int s0 = blockIdx.x * 32;
    const int e0 = blockIdx.y * 32;
    const float* px = x + (long)b * 2048 * 512;
    short* pt = xt + (long)b * 512 * 2048;
    const int tx = threadIdx.x & 31;
    const int ty = threadIdx.x >> 5;   // 0..7
#pragma unroll
    for (int r = 0; r < 32; r += 8)
        tile[ty + r][tx] = f2bf(px[(long)(s0 + ty + r) * 512 + e0 + tx]);
    __syncthreads();
#pragma unroll
    for (int r = 0; r < 32; r += 8)
        pt[(long)(e0 + ty + r) * 2048 + s0 + tx] = tile[tx][ty + r];
}

// ---------------------------------------------------------------------------
// gemm_bt: C[m][n] = sum_k A[m][k]*B[n][k]  (both operands K-contiguous).
// 128x128 tile, BK=32, 4 waves (2x2 of 64x64), 16x16x32 bf16 MFMA.
// NTERMS=3: split precision  acc += Ah*Bh + Ah*Bl + Al*Bh.
// SPLIT_OUT: write hi/lo bf16 pair instead of fp32 (for enc_proj).
// ---------------------------------------------------------------------------
template<int NTERMS, bool SPLIT_OUT>
__global__ __launch_bounds__(256, 2)
void gemm_bt(const short* __restrict__ Ah, const short* __restrict__ Al,
             const short* __restrict__ Bh, const short* __restrict__ Bl,
             float* __restrict__ C, short* __restrict__ Ch, short* __restrict__ Cl,
             int K, int lda, int ldb, int ldc,
             long sA, long sB, long sC)
{
    extern __shared__ char smem_raw[];
    short* As_h = (short*)smem_raw;       // 128*32 shorts = 8 KB
    short* Bs_h = As_h + 128 * 32;
    short* As_l = Bs_h + 128 * 32;        // NTERMS==3 only
    short* Bs_l = As_l + 128 * 32;

    const int tid  = threadIdx.x;
    const int wave = tid >> 6;
    const int lane = tid & 63;
    const int quad = lane >> 4;
    const int l16  = lane & 15;
    const int wm   = (wave >> 1) * 64;
    const int wn   = (wave & 1) * 64;

    const long tile_m = (long)blockIdx.y * 128;
    const long tile_n = (long)blockIdx.x * 128;
    const int  bz     = blockIdx.z;

    const short* pAh = Ah + (long)bz * sA;
    const short* pBh = Bh + (long)bz * sB;
    const short* pAl = (NTERMS == 3) ? (Al + (long)bz * sA) : nullptr;
    const short* pBl = (NTERMS == 3) ? (Bl + (long)bz * sB) : nullptr;

    // staging: thread t -> row t>>2, k-subchunk (t&3)*8; LDS byte off = 16*t
    const int srow = tid >> 2;
    const int skq  = (tid & 3) * 8;
    const int lds_off = srow * 32 + skq;
    const long ga0 = (tile_m + srow) * (long)lda + skq;
    const long gb0 = (tile_n + srow) * (long)ldb + skq;

    f32x4 acc[4][4] = {};

    for (int k0 = 0; k0 < K; k0 += 32) {
        gload_lds16(pAh + ga0 + k0,            As_h + lds_off);
        gload_lds16(pAh + ga0 + 64l * lda + k0, As_h + lds_off + 64 * 32);
        gload_lds16(pBh + gb0 + k0,            Bs_h + lds_off);
        gload_lds16(pBh + gb0 + 64l * ldb + k0, Bs_h + lds_off + 64 * 32);
        if constexpr (NTERMS == 3) {
            gload_lds16(pAl + ga0 + k0,            As_l + lds_off);
            gload_lds16(pAl + ga0 + 64l * lda + k0, As_l + lds_off + 64 * 32);
            gload_lds16(pBl + gb0 + k0,            Bs_l + lds_off);
            gload_lds16(pBl + gb0 + 64l * ldb + k0, Bs_l + lds_off + 64 * 32);
        }
        __syncthreads();   // compiler drains vmcnt before s_barrier

        short8 ah[4], bh[4], al[4], bl[4];
#pragma unroll
        for (int i = 0; i < 4; i++) {
            ah[i] = *(const short8*)&As_h[(wm + i * 16 + l16) * 32 + quad * 8];
            bh[i] = *(const short8*)&Bs_h[(wn + i * 16 + l16) * 32 + quad * 8];
            if constexpr (NTERMS == 3) {
                al[i] = *(const short8*)&As_l[(wm + i * 16 + l16) * 32 + quad * 8];
                bl[i] = *(const short8*)&Bs_l[(wn + i * 16 + l16) * 32 + quad * 8];
            }
        }
#pragma unroll
        for (int i = 0; i < 4; i++)
#pragma unroll
            for (int j = 0; j < 4; j++) {
                acc[i][j] = __builtin_amdgcn_mfma_f32_16x16x32_bf16(ah[i], bh[j], acc[i][j], 0, 0, 0);
                if constexpr (NTERMS == 3) {
                    acc[i][j] = __builtin_amdgcn_mfma_f32_16x16x32_bf16(ah[i], bl[j], acc[i][j], 0, 0, 0);
                    acc[i][j] = __builtin_amdgcn_mfma_f32_16x16x32_bf16(al[i], bh[j], acc[i][j], 0, 0, 0);
                }
            }
        __syncthreads();
    }

    // epilogue: D row = quad*4 + reg, col = lane&15  (m89-verified mapping)
#pragma unroll
    for (int i = 0; i < 4; i++)
#pragma unroll
        for (int j = 0; j < 4; j++) {
            const long row0 = tile_m + wm + i * 16 + quad * 4;
            const long col  = tile_n + wn + j * 16 + l16;
#pragma unroll
            for (int r = 0; r < 4; r++) {
                float v = acc[i][j][r];
                if constexpr (SPLIT_OUT) {
                    long idx = (long)bz * sC + (row0 + r) * (long)ldc + col;
                    short h = f2bf(v);
                    Ch[idx] = h;
                    Cl[idx] = f2bf(v - bf2f(h));
                } else {
                    C[(long)bz * sC + (row0 + r) * (long)ldc + col] = v;
                }
            }
        }
}

// ---------------------------------------------------------------------------
// Row softmax over 2048 fp32 logits; writes P as bf16 in-place (first 4KB of
// each 8KB row).  Safe: every thread consumes its loads before first barrier.
// ---------------------------------------------------------------------------
__global__ __launch_bounds__(256)
void softmax_kernel(float* __restrict__ logits)
{
    const long row = blockIdx.x;
    float* p = logits + row * 2048;
    const int tid = threadIdx.x;
    const int lane = tid & 63, wave = tid >> 6;

    f32x4 v0 = *(const f32x4*)(p + tid * 8);
    f32x4 v1 = *(const f32x4*)(p + tid * 8 + 4);

    float m = fmaxf(fmaxf(fmaxf(v0[0], v0[1]), fmaxf(v0[2], v0[3])),
                    fmaxf(fmaxf(v1[0], v1[1]), fmaxf(v1[2], v1[3])));
#pragma unroll
    for (int o = 32; o > 0; o >>= 1) m = fmaxf(m, __shfl_xor(m, o));

    __shared__ float red[8];
    if (lane == 0) red[wave] = m;
    __syncthreads();
    m = fmaxf(fmaxf(red[0], red[1]), fmaxf(red[2], red[3]));

    float e[8];
    float s = 0.f;
#pragma unroll
    for (int i = 0; i < 4; i++) { e[i] = __expf(v0[i] - m); s += e[i]; }
#pragma unroll
    for (int i = 0; i < 4; i++) { e[4 + i] = __expf(v1[i] - m); s += e[4 + i]; }
#pragma unroll
    for (int o = 32; o > 0; o >>= 1) s += __shfl_xor(s, o);
    if (lane == 0) red[4 + wave] = s;
    __syncthreads();
    const float inv = 1.f / (red[4] + red[5] + red[6] + red[7]);

    short8 ob;
#pragma unroll
    for (int i = 0; i < 8; i++) ob[i] = f2bf(e[i] * inv);
    *(short8*)((short*)p + tid * 8) = ob;
}

// ---------------------------------------------------------------------------
extern "C" void kernel_launch(void* const* d_in, const int* in_sizes, int n_in,
                              void* d_out, int out_size, void* d_ws, size_t ws_size,
                              hipStream_t stream)
{
    const float* enc = (const float*)d_in[0];   // [8,2048,512]
    const float* dec = (const float*)d_in[1];   // [8,2048,512]
    const float* W   = (const float*)d_in[2];   // [512,512]
    float* out = (float*)d_out;                 // [8,2048,512]

    const long BSE = 8l * 2048 * 512;           // 8388608
    const long NW  = 512l * 512;

    char* p = (char*)d_ws;
    auto take = [&](long bytes) { char* r = p; p += (bytes + 255) & ~255l; return r; };
    short* enc_hi = (short*)take(BSE * 2);
    short* enc_lo = (short*)take(BSE * 2);
    short* dec_hi = (short*)take(BSE * 2);
    short* dec_lo = (short*)take(BSE * 2);
    short* ep_hi  = (short*)take(BSE * 2);
    short* ep_lo  = (short*)take(BSE * 2);
    short* enc_t  = (short*)take(BSE * 2);
    short* wt_hi  = (short*)take(NW * 2);
    short* wt_lo  = (short*)take(NW * 2);
    float* logits = (float*)take(8l * 2048 * 2048 * 4);   // total ~253 MB
    (void)ws_size; (void)in_sizes; (void)n_in; (void)out_size;

    split_kernel<<<4096, 256, 0, stream>>>(enc, enc_hi, enc_lo);
    split_kernel<<<4096, 256, 0, stream>>>(dec, dec_hi, dec_lo);
    split_w_kernel<<<1024, 256, 0, stream>>>(W, wt_hi, wt_lo);
    transpose_bf16_kernel<<<dim3(64, 16, 8), 256, 0, stream>>>(enc, enc_t);

    // enc_proj = enc @ W  (M=16384, N=512, K=512), 3-term, split bf16 output
    gemm_bt<3, true><<<dim3(4, 128, 1), 256, 32 * 1024, stream>>>(
        enc_hi, enc_lo, wt_hi, wt_lo, nullptr, ep_hi, ep_lo,
        512, 512, 512, 512, 0, 0, 0);

    // logits[b] = dec[b] @ ep[b]^T  (M=2048, N=2048, K=512) x 8, 3-term
    gemm_bt<3, false><<<dim3(16, 16, 8), 256, 32 * 1024, stream>>>(
        dec_hi, dec_lo, ep_hi, ep_lo, logits, nullptr, nullptr,
        512, 512, 512, 2048, 2048l * 512, 2048l * 512, 2048l * 2048);

    softmax_kernel<<<16384, 256, 0, stream>>>(logits);

    // out[b] = P[b] @ enc[b]  (M=2048, N=512, K=2048) x 8, plain bf16
    // P rows are bf16 packed at stride 4096 shorts inside the logits buffer.
    gemm_bt<1, false><<<dim3(4, 16, 8), 256, 16 * 1024, stream>>>(
        (const short*)logits, nullptr, enc_t, nullptr, out, nullptr, nullptr,
        2048, 4096, 2048, 512, 2048l * 4096, 512l * 2048, 2048l * 512);
}

// Round 2
// 355.785 us; speedup vs baseline: 1.1786x; 1.1786x over previous
//
#include <hip/hip_runtime.h>
#include <cstdint>

// ---------------------------------------------------------------------------
// Attention (Luong general): out = softmax(dec @ (enc@W)^T) @ enc
// B=8, S_enc=S_dec=2048, H=512, fp32 in/out.
//
// bf16 MFMA; split-precision (hi+lo bf16, 3-term) for the two matmuls feeding
// softmax; plain bf16 for PV. Round 2: double-buffered LDS staging in gemm_bt
// (one barrier/iter, prefetch next k-tile before consuming current -> the
// vmcnt(0) barrier drain overlaps a full compute phase) + compact P buffer
// (softmax writes contiguous bf16 P aliased over dead split buffers).
// ---------------------------------------------------------------------------

#define DEVINL __device__ __forceinline__

typedef __attribute__((ext_vector_type(8))) short short8;
typedef __attribute__((ext_vector_type(4))) float f32x4;

DEVINL short f2bf(float x) {
    union { float f; uint32_t u; } v; v.f = x;
    uint32_t r = v.u + 0x7FFFu + ((v.u >> 16) & 1u);   // RNE
    return (short)(r >> 16);
}
DEVINL float bf2f(short h) {
    union { uint32_t u; float f; } v; v.u = ((uint32_t)(uint16_t)h) << 16;
    return v.f;
}

DEVINL void gload_lds16(const void* g, void* l) {
    __builtin_amdgcn_global_load_lds(
        (const __attribute__((address_space(1))) char*)g,
        (__attribute__((address_space(3))) char*)l, 16, 0, 0);
}

// ---------------------------------------------------------------------------
// split fp32 -> (hi, lo) bf16 arrays.  8 elems/thread, exact-cover grids.
// ---------------------------------------------------------------------------
__global__ __launch_bounds__(256)
void split_kernel(const float* __restrict__ x, short* __restrict__ hi,
                  short* __restrict__ lo)
{
    long i = ((long)blockIdx.x * 256 + threadIdx.x) * 8;
    f32x4 a = *(const f32x4*)(x + i);
    f32x4 b = *(const f32x4*)(x + i + 4);
    short8 h, l;
#pragma unroll
    for (int j = 0; j < 4; j++) {
        short ha = f2bf(a[j]); h[j] = ha;     l[j] = f2bf(a[j] - bf2f(ha));
        short hb = f2bf(b[j]); h[4 + j] = hb; l[4 + j] = f2bf(b[j] - bf2f(hb));
    }
    *(short8*)(hi + i) = h;
    *(short8*)(lo + i) = l;
}

// W[512k][512n] -> Wt_hi/lo[n][k]
__global__ __launch_bounds__(256)
void split_w_kernel(const float* __restrict__ w, short* __restrict__ wth,
                    short* __restrict__ wtl)
{
    int idx = blockIdx.x * 256 + threadIdx.x;   // k*512 + n
    int k = idx >> 9, n = idx & 511;
    float v = w[idx];
    short h = f2bf(v);
    wth[(long)n * 512 + k] = h;
    wtl[(long)n * 512 + k] = f2bf(v - bf2f(h));
}

// enc[b][s][e] fp32 -> enc_t[b][e][s] bf16 (PV B-operand)
__global__ __launch_bounds__(256)
void transpose_bf16_kernel(const float* __restrict__ x, short* __restrict__ xt)
{
    __shared__ short tile[32][33];
    const int b  = blockIdx.z;
    const int s0 = blockIdx.x * 32;
    const int e0 = blockIdx.y * 32;
    const float* px = x + (long)b * 2048 * 512;
    short* pt = xt + (long)b * 512 * 2048;
    const int tx = threadIdx.x & 31;
    const int ty = threadIdx.x >> 5;   // 0..7
#pragma unroll
    for (int r = 0; r < 32; r += 8)
        tile[ty + r][tx] = f2bf(px[(long)(s0 + ty + r) * 512 + e0 + tx]);
    __syncthreads();
#pragma unroll
    for (int r = 0; r < 32; r += 8)
        pt[(long)(e0 + ty + r) * 2048 + s0 + tx] = tile[tx][ty + r];
}

// ---------------------------------------------------------------------------
// gemm_bt: C[m][n] = sum_k A[m][k]*B[n][k]  (both operands K-contiguous).
// 128x128 tile, BK=32, 4 waves (2x2 of 64x64), 16x16x32 bf16 MFMA.
// Double-buffered LDS: stage(k+1) issued right after the barrier, before
// consuming tile k -> the compiler's vmcnt(0) drain at the NEXT barrier
// waits on loads that have had a full compute phase to land.
// Hazard note: one barrier/iter suffices -- a wave reaching barrier B_{k+1}
// has already consumed its iter-k ds_reads (lgkm waits precede MFMA issue),
// so stage(k+2) may overwrite that buffer after B_{k+1}.
// ---------------------------------------------------------------------------
template<int NTERMS, bool SPLIT_OUT>
__global__ __launch_bounds__(256, 2)
void gemm_bt(const short* __restrict__ Ah, const short* __restrict__ Al,
             const short* __restrict__ Bh, const short* __restrict__ Bl,
             float* __restrict__ C, short* __restrict__ Ch, short* __restrict__ Cl,
             int K, int lda, int ldb, int ldc,
             long sA, long sB, long sC)
{
    extern __shared__ char smem_raw[];
    constexpr int OPS = (NTERMS == 3) ? 4 : 2;     // operand planes per set
    constexpr int SET = 128 * 32 * OPS;            // shorts per buffer set
    short* smem = (short*)smem_raw;                // 2 sets

    const int tid  = threadIdx.x;
    const int wave = tid >> 6;
    const int lane = tid & 63;
    const int quad = lane >> 4;
    const int l16  = lane & 15;
    const int wm   = (wave >> 1) * 64;
    const int wn   = (wave & 1) * 64;

    const long tile_m = (long)blockIdx.y * 128;
    const long tile_n = (long)blockIdx.x * 128;
    const int  bz     = blockIdx.z;

    const short* pAh = Ah + (long)bz * sA;
    const short* pBh = Bh + (long)bz * sB;
    const short* pAl = (NTERMS == 3) ? (Al + (long)bz * sA) : nullptr;
    const short* pBl = (NTERMS == 3) ? (Bl + (long)bz * sB) : nullptr;

    // staging: thread t -> row t>>2, k-subchunk (t&3)*8; LDS byte off = 16*t
    const int srow = tid >> 2;
    const int skq  = (tid & 3) * 8;
    const int lds_off = srow * 32 + skq;
    const long ga0 = (tile_m + srow) * (long)lda + skq;
    const long gb0 = (tile_n + srow) * (long)ldb + skq;

    auto stage = [&](int k0, int buf) {
        short* s   = smem + buf * SET;
        short* ash = s;
        short* bsh = s + 128 * 32;
        gload_lds16(pAh + ga0 + k0,             ash + lds_off);
        gload_lds16(pAh + ga0 + 64l * lda + k0, ash + lds_off + 64 * 32);
        gload_lds16(pBh + gb0 + k0,             bsh + lds_off);
        gload_lds16(pBh + gb0 + 64l * ldb + k0, bsh + lds_off + 64 * 32);
        if constexpr (NTERMS == 3) {
            short* asl = s + 2 * 128 * 32;
            short* bsl = s + 3 * 128 * 32;
            gload_lds16(pAl + ga0 + k0,             asl + lds_off);
            gload_lds16(pAl + ga0 + 64l * lda + k0, asl + lds_off + 64 * 32);
            gload_lds16(pBl + gb0 + k0,             bsl + lds_off);
            gload_lds16(pBl + gb0 + 64l * ldb + k0, bsl + lds_off + 64 * 32);
        }
    };

    f32x4 acc[4][4] = {};
    stage(0, 0);
    int cur = 0;

    for (int k0 = 0; k0 < K; k0 += 32) {
        __syncthreads();                    // drains vmcnt: stage(cur) done
        if (k0 + 32 < K) stage(k0 + 32, cur ^ 1);   // prefetch next tile

        short* s   = smem + cur * SET;
        short* ash = s;
        short* bsh = s + 128 * 32;
        short* asl = s + 2 * 128 * 32;
        short* bsl = s + 3 * 128 * 32;

        short8 ah[4], bh[4], al[4], bl[4];
#pragma unroll
        for (int i = 0; i < 4; i++) {
            ah[i] = *(const short8*)&ash[(wm + i * 16 + l16) * 32 + quad * 8];
            bh[i] = *(const short8*)&bsh[(wn + i * 16 + l16) * 32 + quad * 8];
            if constexpr (NTERMS == 3) {
                al[i] = *(const short8*)&asl[(wm + i * 16 + l16) * 32 + quad * 8];
                bl[i] = *(const short8*)&bsl[(wn + i * 16 + l16) * 32 + quad * 8];
            }
        }
#pragma unroll
        for (int i = 0; i < 4; i++)
#pragma unroll
            for (int j = 0; j < 4; j++) {
                acc[i][j] = __builtin_amdgcn_mfma_f32_16x16x32_bf16(ah[i], bh[j], acc[i][j], 0, 0, 0);
                if constexpr (NTERMS == 3) {
                    acc[i][j] = __builtin_amdgcn_mfma_f32_16x16x32_bf16(ah[i], bl[j], acc[i][j], 0, 0, 0);
                    acc[i][j] = __builtin_amdgcn_mfma_f32_16x16x32_bf16(al[i], bh[j], acc[i][j], 0, 0, 0);
                }
            }
        cur ^= 1;
    }

    // epilogue: D row = quad*4 + reg, col = lane&15  (m89-verified mapping)
#pragma unroll
    for (int i = 0; i < 4; i++)
#pragma unroll
        for (int j = 0; j < 4; j++) {
            const long row0 = tile_m + wm + i * 16 + quad * 4;
            const long col  = tile_n + wn + j * 16 + l16;
#pragma unroll
            for (int r = 0; r < 4; r++) {
                float v = acc[i][j][r];
                if constexpr (SPLIT_OUT) {
                    long idx = (long)bz * sC + (row0 + r) * (long)ldc + col;
                    short h = f2bf(v);
                    Ch[idx] = h;
                    Cl[idx] = f2bf(v - bf2f(h));
                } else {
                    C[(long)bz * sC + (row0 + r) * (long)ldc + col] = v;
                }
            }
        }
}

// ---------------------------------------------------------------------------
// Row softmax over 2048 fp32 logits; writes P as contiguous bf16.
// ---------------------------------------------------------------------------
__global__ __launch_bounds__(256)
void softmax_kernel(const float* __restrict__ logits, short* __restrict__ P)
{
    const long row = blockIdx.x;
    const float* p = logits + row * 2048;
    const int tid = threadIdx.x;
    const int lane = tid & 63, wave = tid >> 6;

    f32x4 v0 = *(const f32x4*)(p + tid * 8);
    f32x4 v1 = *(const f32x4*)(p + tid * 8 + 4);

    float m = fmaxf(fmaxf(fmaxf(v0[0], v0[1]), fmaxf(v0[2], v0[3])),
                    fmaxf(fmaxf(v1[0], v1[1]), fmaxf(v1[2], v1[3])));
#pragma unroll
    for (int o = 32; o > 0; o >>= 1) m = fmaxf(m, __shfl_xor(m, o));

    __shared__ float red[8];
    if (lane == 0) red[wave] = m;
    __syncthreads();
    m = fmaxf(fmaxf(red[0], red[1]), fmaxf(red[2], red[3]));

    float e[8];
    float s = 0.f;
#pragma unroll
    for (int i = 0; i < 4; i++) { e[i] = __expf(v0[i] - m); s += e[i]; }
#pragma unroll
    for (int i = 0; i < 4; i++) { e[4 + i] = __expf(v1[i] - m); s += e[4 + i]; }
#pragma unroll
    for (int o = 32; o > 0; o >>= 1) s += __shfl_xor(s, o);
    if (lane == 0) red[4 + wave] = s;
    __syncthreads();
    const float inv = 1.f / (red[4] + red[5] + red[6] + red[7]);

    short8 ob;
#pragma unroll
    for (int i = 0; i < 8; i++) ob[i] = f2bf(e[i] * inv);
    *(short8*)(P + row * 2048 + tid * 8) = ob;
}

// ---------------------------------------------------------------------------
extern "C" void kernel_launch(void* const* d_in, const int* in_sizes, int n_in,
                              void* d_out, int out_size, void* d_ws, size_t ws_size,
                              hipStream_t stream)
{
    const float* enc = (const float*)d_in[0];   // [8,2048,512]
    const float* dec = (const float*)d_in[1];   // [8,2048,512]
    const float* W   = (const float*)d_in[2];   // [512,512]
    float* out = (float*)d_out;                 // [8,2048,512]

    const long BSE = 8l * 2048 * 512;           // 8388608
    const long NW  = 512l * 512;

    char* p = (char*)d_ws;
    auto take = [&](long bytes) { char* r = p; p += (bytes + 255) & ~255l; return r; };
    short* enc_hi = (short*)take(BSE * 2);
    short* enc_lo = (short*)take(BSE * 2);
    short* dec_hi = (short*)take(BSE * 2);
    short* dec_lo = (short*)take(BSE * 2);
    short* ep_hi  = (short*)take(BSE * 2);
    short* ep_lo  = (short*)take(BSE * 2);
    short* enc_t  = (short*)take(BSE * 2);
    short* wt_hi  = (short*)take(NW * 2);
    short* wt_lo  = (short*)take(NW * 2);
    float* logits = (float*)take(8l * 2048 * 2048 * 4);   // total ~253 MB
    // P [8][2048][2048] bf16 = 67.1 MB: aliases enc_hi..dec_lo (4 x 16.78 MB,
    // contiguous, all dead once softmax runs).
    short* Pbuf = enc_hi;
    (void)ws_size; (void)in_sizes; (void)n_in; (void)out_size;

    split_kernel<<<4096, 256, 0, stream>>>(enc, enc_hi, enc_lo);
    split_kernel<<<4096, 256, 0, stream>>>(dec, dec_hi, dec_lo);
    split_w_kernel<<<1024, 256, 0, stream>>>(W, wt_hi, wt_lo);
    transpose_bf16_kernel<<<dim3(64, 16, 8), 256, 0, stream>>>(enc, enc_t);

    // enc_proj = enc @ W  (M=16384, N=512, K=512), 3-term, split bf16 output
    gemm_bt<3, true><<<dim3(4, 128, 1), 256, 64 * 1024, stream>>>(
        enc_hi, enc_lo, wt_hi, wt_lo, nullptr, ep_hi, ep_lo,
        512, 512, 512, 512, 0, 0, 0);

    // logits[b] = dec[b] @ ep[b]^T  (M=2048, N=2048, K=512) x 8, 3-term
    gemm_bt<3, false><<<dim3(16, 16, 8), 256, 64 * 1024, stream>>>(
        dec_hi, dec_lo, ep_hi, ep_lo, logits, nullptr, nullptr,
        512, 512, 512, 2048, 2048l * 512, 2048l * 512, 2048l * 2048);

    softmax_kernel<<<16384, 256, 0, stream>>>(logits, Pbuf);

    // out[b] = P[b] @ enc[b]  (M=2048, N=512, K=2048) x 8, plain bf16
    gemm_bt<1, false><<<dim3(4, 16, 8), 256, 32 * 1024, stream>>>(
        Pbuf, nullptr, enc_t, nullptr, out, nullptr, nullptr,
        2048, 2048, 2048, 512, 2048l * 2048, 512l * 2048, 2048l * 512);
}